// Round 5
// baseline (122.655 us; speedup 1.0000x reference)
//
#include <hip/hip_runtime.h>

#define NUM_NETS     100000
#define PINS_PER_NET 5
#define NUM_PINS     (NUM_NETS * PINS_PER_NET)
#define NB           512
#define BIN_H        1.953125f          /* 1000/512, exact in fp32 */
#define INV_H        0.512f             /* 512/1000 */
#define OUT_SCALE    (1.0f / 195.3125f) /* 1/(BIN_SIZE_X * 100 tracks) */

#define TILE         64
#define NTX          (NB / TILE)        /* 8 */
#define NTILES       (NTX * NTX)        /* 64 */
#define STRIPE       8
#define NSTRIPE      (NB / STRIPE)      /* 64 */
#define NBLK         ((NUM_NETS + 1023) / 1024)   /* 98 */
#define ITEM_CAP     524288             /* >= ~414K actual emissions */

// ---------------------------------------------------------------------------
// Cluster->tile enumeration shared by count and emit passes (must be identical)
// ---------------------------------------------------------------------------
template <class F>
__device__ __forceinline__ void for_each_tile(int kx1, int kx2, int ky1, int ky2,
                                              F&& f) {
#pragma unroll
    for (int cx = 0; cx < 2; ++cx) {
        int kx  = cx ? kx2 : kx1;
        int txa = kx >> 6;
        int txb = min(kx + 1, NB - 1) >> 6;
#pragma unroll
        for (int cy = 0; cy < 2; ++cy) {
            int ky  = cy ? ky2 : ky1;
            int tya = ky >> 6;
            int tyb = min(ky + 1, NB - 1) >> 6;
            f(cx, cy, kx, ky, txa * NTX + tya);
            if (txb != txa)               f(cx, cy, kx, ky, txb * NTX + tya);
            if (tyb != tya)               f(cx, cy, kx, ky, txa * NTX + tyb);
            if (txb != txa && tyb != tya) f(cx, cy, kx, ky, txb * NTX + tyb);
        }
    }
}

// ---------------------------------------------------------------------------
// A: bbox -> recA {xmn,xmx,ymn,ymx}, recB {wh,wv,pkx,pky}; per-block tile counts
// ---------------------------------------------------------------------------
__global__ __launch_bounds__(1024) void bbox_count_kernel(
        const float* __restrict__ pin_pos,
        const int*   __restrict__ flat_netpin,
        const float* __restrict__ net_weights,
        float4* __restrict__ recA, float4* __restrict__ recB,
        int* __restrict__ pcount) {
    __shared__ int lcnt[NTILES];
    int tid = threadIdx.x;
    if (tid < NTILES) lcnt[tid] = 0;
    __syncthreads();

    int n = blockIdx.x * 1024 + tid;
    if (n < NUM_NETS) {
        float xmn = 1e30f, xmx = -1e30f, ymn = 1e30f, ymx = -1e30f;
#pragma unroll
        for (int p = 0; p < PINS_PER_NET; ++p) {
            int pi  = flat_netpin[n * PINS_PER_NET + p];
            float x = pin_pos[pi];
            float y = pin_pos[NUM_PINS + pi];
            xmn = fminf(xmn, x); xmx = fmaxf(xmx, x);
            ymn = fminf(ymn, y); ymx = fmaxf(ymx, y);
        }
        float w = net_weights[n];
        int kx1 = min(NB - 1, (int)(xmn * INV_H));
        int kx2 = min(NB - 1, (int)(xmx * INV_H));
        int ky1 = min(NB - 1, (int)(ymn * INV_H));
        int ky2 = min(NB - 1, (int)(ymx * INV_H));
        recA[n] = make_float4(xmn, xmx, ymn, ymx);
        recB[n] = make_float4(w / (ymx - ymn), w / (xmx - xmn),
                              __uint_as_float((unsigned)kx1 | ((unsigned)kx2 << 16)),
                              __uint_as_float((unsigned)ky1 | ((unsigned)ky2 << 16)));
        for_each_tile(kx1, kx2, ky1, ky2,
            [&](int, int, int, int, int tl) { atomicAdd(&lcnt[tl], 1); });
    }
    __syncthreads();
    if (tid < NTILES) pcount[blockIdx.x * NTILES + tid] = lcnt[tid];
}

// ---------------------------------------------------------------------------
// B: one wave — per-tile totals, exclusive offsets, cursor init
// ---------------------------------------------------------------------------
__global__ void offsets_kernel(const int* __restrict__ pcount,
                               int* __restrict__ count,
                               int* __restrict__ goff,
                               int* __restrict__ gcursor) {
    int t = threadIdx.x;          /* 64 threads = 1 wave */
    int c = 0;
    for (int b = 0; b < NBLK; ++b) c += pcount[b * NTILES + t];
    count[t] = c;
    int inc = c;
#pragma unroll
    for (int o = 1; o < 64; o <<= 1) {
        int a = __shfl_up(inc, o);
        if (t >= o) inc += a;
    }
    int excl = inc - c;
    goff[t] = excl;
    gcursor[t] = excl;
}

// ---------------------------------------------------------------------------
// C: emit items {key=(kx,ky), val={x,y,±wh,±wv}} into exact per-tile segments
// ---------------------------------------------------------------------------
__global__ __launch_bounds__(1024) void emit_kernel(
        const float4* __restrict__ recA, const float4* __restrict__ recB,
        int* __restrict__ gcursor,
        unsigned* __restrict__ keys, float4* __restrict__ vals) {
    __shared__ int lcnt[NTILES];
    __shared__ int lbase[NTILES];
    int tid = threadIdx.x;
    if (tid < NTILES) lcnt[tid] = 0;
    __syncthreads();

    int n = blockIdx.x * 1024 + tid;
    bool valid = n < NUM_NETS;
    float4 ra, rb;
    int kx1 = 0, kx2 = 0, ky1 = 0, ky2 = 0;
    if (valid) {
        ra = recA[n]; rb = recB[n];
        unsigned pkx = __float_as_uint(rb.z), pky = __float_as_uint(rb.w);
        kx1 = (int)(pkx & 0xffffu); kx2 = (int)(pkx >> 16);
        ky1 = (int)(pky & 0xffffu); ky2 = (int)(pky >> 16);
        for_each_tile(kx1, kx2, ky1, ky2,
            [&](int, int, int, int, int tl) { atomicAdd(&lcnt[tl], 1); });
    }
    __syncthreads();
    if (tid < NTILES) {
        lbase[tid] = atomicAdd(&gcursor[tid], lcnt[tid]);
        lcnt[tid] = 0;
    }
    __syncthreads();
    if (valid) {
        float xmn = ra.x, xmx = ra.y, ymn = ra.z, ymx = ra.w;
        float wh = rb.x, wv = rb.y;
        for_each_tile(kx1, kx2, ky1, ky2,
            [&](int cx, int cy, int kx, int ky, int tl) {
                int rank = atomicAdd(&lcnt[tl], 1);
                int pos  = lbase[tl] + rank;
                if (pos < ITEM_CAP) {
                    keys[pos] = (unsigned)kx | ((unsigned)ky << 16);
                    float s = (cx ^ cy) ? -1.0f : 1.0f;
                    vals[pos] = make_float4(cx ? xmx : xmn, cy ? ymx : ymn,
                                            s * wh, s * wv);
                }
            });
    }
}

// ---------------------------------------------------------------------------
// D: per-tile dense accumulate. Block = (slice s, tile tl); LDS 2x64x64.
// ---------------------------------------------------------------------------
__global__ __launch_bounds__(1024) void accum_kernel(
        const unsigned* __restrict__ keys, const float4* __restrict__ vals,
        const int* __restrict__ count, const int* __restrict__ goff,
        float* __restrict__ reps, int S) {
    __shared__ float acc[2][TILE * TILE];   /* 32 KB */
    int tl  = blockIdx.x & (NTILES - 1);
    int s   = blockIdx.x >> 6;
    int tx0 = (tl >> 3) * TILE;
    int ty0 = (tl & 7) * TILE;
    int tid = threadIdx.x;

    float4* a4 = (float4*)&acc[0][0];
#pragma unroll
    for (int k = tid; k < 2 * TILE * TILE / 4; k += 1024)
        a4[k] = make_float4(0.f, 0.f, 0.f, 0.f);
    __syncthreads();

    int i0  = goff[tl];
    int cnt = min(count[tl], ITEM_CAP - i0);
    for (int q = s * 1024 + tid; q < cnt; q += S * 1024) {
        unsigned key = keys[i0 + q];
        float4 v = vals[i0 + q];
        int kx = (int)(key & 0xffffu), ky = (int)(key >> 16);
        float dx0 = (kx + 1) * BIN_H - v.x;
        float dx1 = v.x - kx * BIN_H;
        float dy0 = (ky + 1) * BIN_H - v.y;
        float dy1 = v.y - ky * BIN_H;
        int gx = kx - tx0, gy = ky - ty0;
        bool x0 = (unsigned)gx < TILE,      x1 = (unsigned)(gx + 1) < TILE;
        bool y0 = (unsigned)gy < TILE,      y1 = (unsigned)(gy + 1) < TILE;
        if (x0 && y0) { float p = dx0 * dy0; int i = gx * TILE + gy;
            atomicAdd(&acc[0][i], v.z * p); atomicAdd(&acc[1][i], v.w * p); }
        if (x0 && y1) { float p = dx0 * dy1; int i = gx * TILE + gy + 1;
            atomicAdd(&acc[0][i], v.z * p); atomicAdd(&acc[1][i], v.w * p); }
        if (x1 && y0) { float p = dx1 * dy0; int i = (gx + 1) * TILE + gy;
            atomicAdd(&acc[0][i], v.z * p); atomicAdd(&acc[1][i], v.w * p); }
        if (x1 && y1) { float p = dx1 * dy1; int i = (gx + 1) * TILE + gy + 1;
            atomicAdd(&acc[0][i], v.z * p); atomicAdd(&acc[1][i], v.w * p); }
    }
    __syncthreads();

    float4* dst = (float4*)(reps + (size_t)blockIdx.x * (2 * TILE * TILE));
#pragma unroll
    for (int k = tid; k < 2 * TILE * TILE / 4; k += 1024)
        dst[k] = a4[k];
}

// ---------------------------------------------------------------------------
// E: reduce S replicas + inclusive y-scan (shuffle). Block = grid row x.
// ---------------------------------------------------------------------------
__global__ void reduce_rowscan_kernel(const float* __restrict__ reps,
                                      float* __restrict__ Uh,
                                      float* __restrict__ Uv, int S) {
    __shared__ float swh[8], swv[8];
    int x = blockIdx.x, tid = threadIdx.x;
    int lane = tid & 63, wid = tid >> 6;
    int tl  = (x >> 6) * NTX + (tid >> 6);
    int off = (x & 63) * TILE + (tid & 63);
    float h = 0.f, v = 0.f;
    for (int s = 0; s < S; ++s) {
        const float* base = reps + (size_t)(s * NTILES + tl) * (2 * TILE * TILE);
        h += base[off];
        v += base[TILE * TILE + off];
    }
#pragma unroll
    for (int o = 1; o < 64; o <<= 1) {
        float a = __shfl_up(h, o);
        float b = __shfl_up(v, o);
        if (lane >= o) { h += a; v += b; }
    }
    if (lane == 63) { swh[wid] = h; swv[wid] = v; }
    __syncthreads();
    float oh = 0.f, ov = 0.f;
    for (int j = 0; j < wid; ++j) { oh += swh[j]; ov += swv[j]; }
    Uh[x * NB + tid] = h + oh;
    Uv[x * NB + tid] = v + ov;
}

// ---------------------------------------------------------------------------
// F: per-stripe partial column scans + totals (2D grid over columns)
// ---------------------------------------------------------------------------
__global__ void colscan_partial_kernel(float* __restrict__ Uh,
                                       float* __restrict__ Uv,
                                       float* __restrict__ totH,
                                       float* __restrict__ totV) {
    int s = blockIdx.x;
    int t = blockIdx.y * blockDim.x + threadIdx.x;
    float h = 0.f, v = 0.f;
#pragma unroll
    for (int i = 0; i < STRIPE; ++i) {
        int row = s * STRIPE + i;
        h += Uh[row * NB + t];  Uh[row * NB + t] = h;
        v += Uv[row * NB + t];  Uv[row * NB + t] = v;
    }
    totH[s * NB + t] = h;
    totV[s * NB + t] = v;
}

// ---------------------------------------------------------------------------
// G: stripe offsets + fused epilogue
// ---------------------------------------------------------------------------
__global__ void colscan_finish_kernel(const float* __restrict__ Uh,
                                      const float* __restrict__ Uv,
                                      const float* __restrict__ totH,
                                      const float* __restrict__ totV,
                                      float* __restrict__ out) {
    int s = blockIdx.x;
    int t = blockIdx.y * blockDim.x + threadIdx.x;
    float offh = 0.f, offv = 0.f;
    for (int s2 = 0; s2 < s; ++s2) {
        offh += totH[s2 * NB + t];
        offv += totV[s2 * NB + t];
    }
#pragma unroll
    for (int i = 0; i < STRIPE; ++i) {
        int row = s * STRIPE + i;
        float h = fabsf(Uh[row * NB + t] + offh) * OUT_SCALE;
        float v = fabsf(Uv[row * NB + t] + offv) * OUT_SCALE;
        float r = fmaxf(h, v);
        out[row * NB + t] = fminf(fmaxf(r * r, 0.5f), 2.0f);
    }
}

// ---------------------------------------------------------------------------
// Fallback (tiny workspace): global-atomic scatter + scans
// ---------------------------------------------------------------------------
__global__ void scatter_kernel(const float* __restrict__ pin_pos,
                               const int*   __restrict__ flat_netpin,
                               const float* __restrict__ net_weights,
                               float* __restrict__ Uh,
                               float* __restrict__ Uv) {
    int n = blockIdx.x * blockDim.x + threadIdx.x;
    if (n >= NUM_NETS) return;
    float xmn = 1e30f, xmx = -1e30f, ymn = 1e30f, ymx = -1e30f;
#pragma unroll
    for (int p = 0; p < PINS_PER_NET; ++p) {
        int pi  = flat_netpin[n * PINS_PER_NET + p];
        float x = pin_pos[pi];
        float y = pin_pos[NUM_PINS + pi];
        xmn = fminf(xmn, x); xmx = fmaxf(xmx, x);
        ymn = fminf(ymn, y); ymx = fmaxf(ymx, y);
    }
    float w  = net_weights[n];
    float wh = w / (ymx - ymn), wv = w / (xmx - xmn);
    int kx1 = min(NB - 1, (int)(xmn * INV_H));
    int kx2 = min(NB - 1, (int)(xmx * INV_H));
    int ky1 = min(NB - 1, (int)(ymn * INV_H));
    int ky2 = min(NB - 1, (int)(ymx * INV_H));
    int   xi[4] = { kx1, kx1 + 1, kx2, kx2 + 1 };
    float xv[4] = { (kx1 + 1) * BIN_H - xmn,  xmn - kx1 * BIN_H,
                    xmx - (kx2 + 1) * BIN_H,  kx2 * BIN_H - xmx };
    int   yi[4] = { ky1, ky1 + 1, ky2, ky2 + 1 };
    float yv[4] = { (ky1 + 1) * BIN_H - ymn,  ymn - ky1 * BIN_H,
                    ymx - (ky2 + 1) * BIN_H,  ky2 * BIN_H - ymx };
#pragma unroll
    for (int a = 0; a < 4; ++a) {
        if (xi[a] >= NB) continue;
#pragma unroll
        for (int b = 0; b < 4; ++b) {
            if (yi[b] >= NB) continue;
            float prod = xv[a] * yv[b];
            atomicAdd(&Uh[xi[a] * NB + yi[b]], wh * prod);
            atomicAdd(&Uv[xi[a] * NB + yi[b]], wv * prod);
        }
    }
}

__global__ void row_scan_kernel(float* __restrict__ Uh, float* __restrict__ Uv) {
    __shared__ float sh[NB];
    __shared__ float sv[NB];
    int r = blockIdx.x, t = threadIdx.x;
    sh[t] = Uh[r * NB + t];
    sv[t] = Uv[r * NB + t];
    __syncthreads();
#pragma unroll
    for (int off = 1; off < NB; off <<= 1) {
        float a = (t >= off) ? sh[t - off] : 0.0f;
        float b = (t >= off) ? sv[t - off] : 0.0f;
        __syncthreads();
        sh[t] += a; sv[t] += b;
        __syncthreads();
    }
    Uh[r * NB + t] = sh[t];
    Uv[r * NB + t] = sv[t];
}

extern "C" void kernel_launch(void* const* d_in, const int* in_sizes, int n_in,
                              void* d_out, int out_size, void* d_ws, size_t ws_size,
                              hipStream_t stream) {
    const float* pin_pos     = (const float*)d_in[0];
    const int*   flat_netpin = (const int*)d_in[2];
    const float* net_weights = (const float*)d_in[3];
    float* out = (float*)d_out;
    float* ws  = (float*)d_ws;

    /* layout (floats, all float4-aligned):
       recA[400K] recB[400K] pcount[8192] count[64] goff[128] gcursor[64]
       keys[ITEM_CAP] vals[4*ITEM_CAP] Uh[256K] Uv[256K] totH[32K] totV[32K]
       reps[S*512K] */
    const size_t GRID = (size_t)NB * NB;
    const size_t TOT  = (size_t)NSTRIPE * NB;
    const size_t REP1 = (size_t)NTILES * 2 * TILE * TILE;

    size_t o_recA = 0;
    size_t o_recB = o_recA + (size_t)NUM_NETS * 4;
    size_t o_pcnt = o_recB + (size_t)NUM_NETS * 4;
    size_t o_cnt  = o_pcnt + 8192;
    size_t o_goff = o_cnt + 64;
    size_t o_gcur = o_goff + 128;
    size_t o_keys = o_gcur + 64;
    size_t o_vals = o_keys + ITEM_CAP;
    size_t o_Uh   = o_vals + 4 * (size_t)ITEM_CAP;
    size_t o_Uv   = o_Uh + GRID;
    size_t o_totH = o_Uv + GRID;
    size_t o_totV = o_totH + TOT;
    size_t o_reps = o_totV + TOT;

    int S = 0;
    for (int cand = 8; cand >= 1; cand >>= 1) {
        if (ws_size >= (o_reps + (size_t)cand * REP1) * sizeof(float)) { S = cand; break; }
    }

    if (S == 0) {
        float* Uh = ws;
        float* Uv = ws + GRID;
        float* totH = Uv + GRID;
        float* totV = totH + TOT;
        hipMemsetAsync(ws, 0, 2 * GRID * sizeof(float), stream);
        scatter_kernel<<<(NUM_NETS + 255) / 256, 256, 0, stream>>>(
            pin_pos, flat_netpin, net_weights, Uh, Uv);
        row_scan_kernel<<<NB, NB, 0, stream>>>(Uh, Uv);
        colscan_partial_kernel<<<dim3(NSTRIPE, 1), NB, 0, stream>>>(Uh, Uv, totH, totV);
        colscan_finish_kernel<<<dim3(NSTRIPE, 1), NB, 0, stream>>>(Uh, Uv, totH, totV, out);
        return;
    }

    float4*   recA = (float4*)(ws + o_recA);
    float4*   recB = (float4*)(ws + o_recB);
    int*      pcnt = (int*)(ws + o_pcnt);
    int*      cnt  = (int*)(ws + o_cnt);
    int*      goff = (int*)(ws + o_goff);
    int*      gcur = (int*)(ws + o_gcur);
    unsigned* keys = (unsigned*)(ws + o_keys);
    float4*   vals = (float4*)(ws + o_vals);
    float*    Uh   = ws + o_Uh;
    float*    Uv   = ws + o_Uv;
    float*    totH = ws + o_totH;
    float*    totV = ws + o_totV;
    float*    reps = ws + o_reps;

    bbox_count_kernel<<<NBLK, 1024, 0, stream>>>(
        pin_pos, flat_netpin, net_weights, recA, recB, pcnt);

    offsets_kernel<<<1, 64, 0, stream>>>(pcnt, cnt, goff, gcur);

    emit_kernel<<<NBLK, 1024, 0, stream>>>(recA, recB, gcur, keys, vals);

    accum_kernel<<<NTILES * S, 1024, 0, stream>>>(keys, vals, cnt, goff, reps, S);

    reduce_rowscan_kernel<<<NB, NB, 0, stream>>>(reps, Uh, Uv, S);

    colscan_partial_kernel<<<dim3(NSTRIPE, 4), 128, 0, stream>>>(Uh, Uv, totH, totV);

    colscan_finish_kernel<<<dim3(NSTRIPE, 4), 128, 0, stream>>>(Uh, Uv, totH, totV, out);
}